// Round 2
// baseline (212.686 us; speedup 1.0000x reference)
//
#include <hip/hip_runtime.h>

#define CCOL 10
#define TPB 256
#define NBLOCKS 1024            // persistent; 4 blocks/CU (VGPR-capped at 16 waves/CU)

// Native vector types: __builtin_nontemporal_load requires scalar/native-vector pointee.
typedef float v4f __attribute__((ext_vector_type(4)));
typedef float v2f __attribute__((ext_vector_type(2)));
#define NT(p) __builtin_nontemporal_load(p)   // zero-reuse stream (R8: NT both streams best)

// R12: single-kernel. Read path is empirically ceiling-bound at ~3.5 TB/s across six
// structural/path variants (R8-R11: LDS-staged NT / cached / mixed / depth-2 / split /
// register-direct NT all <= 3.5; external copy ubench read-side ~3.15). ce compute is
// at that roofline within 1%. The last controllable cost is the second dispatch:
// fold reduce_kernel into ce via ticket/last-block (rocPRIM idiom). The ticket is a
// __device__ global that survives iterations (modulo NBLOCKS finds the last block) --
// immune to workspace re-poisoning. Last block runs the IDENTICAL reduction tree as
// the old reduce_kernel, so the output is bitwise unchanged.

__device__ unsigned int g_ticket = 0u;

__device__ __forceinline__ float horner9(const float c[9], float x) {
    float v = c[8];
#pragma unroll
    for (int i = 7; i >= 0; i--) v = fmaf(v, x, c[i]);
    return v;
}

// exp-poly one v4f -> e[base..base+3]
#define EXP4(v, base)                          \
    e[(base) + 0] = horner9(ec, (v).x);        \
    e[(base) + 1] = horner9(ec, (v).y);        \
    e[(base) + 2] = horner9(ec, (v).z);        \
    e[(base) + 3] = horner9(ec, (v).w);

// log-poly + dot for one v4f of targets; comps 0,1 lie in row r0 (inv i0v),
// comps 2,3 in row r1 = r0 + (pos==8) (inv i1v). i1v==i0v when no straddle.
#define LOGDOT(tv, base, i0v, i1v)                                        \
    local = fmaf((tv).x, horner9(lc, e[(base) + 0] * (i0v)), local);      \
    local = fmaf((tv).y, horner9(lc, e[(base) + 1] * (i0v)), local);      \
    local = fmaf((tv).z, horner9(lc, e[(base) + 2] * (i1v)), local);      \
    local = fmaf((tv).w, horner9(lc, e[(base) + 3] * (i1v)), local);

__global__ __launch_bounds__(TPB, 4) void ce_kernel(
    const float* __restrict__ x, const float* __restrict__ tgt,
    const float* __restrict__ exp_c, const float* __restrict__ inv_c,
    const float* __restrict__ log_c, const int* __restrict__ iters_p,
    float* __restrict__ partials, float* __restrict__ out,
    float neg_inv_b, int npairs, int nchunks)
{
    // Per-wave scratch: 640 f32 pair-partials ([128 rows][5 slots]) + 128 f32 inv,
    // padded to 1024 f32 per wave. 16 KiB/block.
    __shared__ __align__(16) float lds[4 * 1024];
    __shared__ int s_last;

    // Coefficients: uniform -> SGPR broadcast.
    float ec[9], ic[5], lc[9];
#pragma unroll
    for (int i = 0; i < 9; i++) ec[i] = exp_c[i];
#pragma unroll
    for (int i = 0; i < 5; i++) ic[i] = inv_c[i];
#pragma unroll
    for (int i = 0; i < 9; i++) lc[i] = log_c[i];
    const int niter = iters_p[0];

    const int tid  = threadIdx.x;
    const int lane = tid & 63;
    const int w    = tid >> 6;
    const int wg   = blockIdx.x * 4 + w;      // global wave id
    const int W    = gridDim.x * 4;           // total waves

    float* const part = lds + w * 1024;       // pair-partials [128][5]
    float* const linv = part + 640;           // per-row inv [128]

    // Loop-invariant per-lane geometry. Flat float index of reg k comp 0 within a
    // chunk (64 pairs = 128 rows = 1280 floats) is b = 256*k + 4*lane; chunk bases
    // are multiples of 1280 so rows never cross chunks. pos = b%10 is even.
    const float* pa0; const float* pa1; const float* pb0; const float* pb1;
    const float* pc0; const float* pc1; const float* pd0; const float* pd1;
    const float* pe0; const float* pe1;
    {
        int r0[5], r1[5];
#pragma unroll
        for (int k = 0; k < 5; k++) {
            int b = 256 * k + 4 * lane;
            int r = b / 10;
            int pos = b - 10 * r;
            r0[k] = r;
            r1[k] = r + (pos == 8 ? 1 : 0);
        }
        pa0 = linv + r0[0]; pa1 = linv + r1[0];
        pb0 = linv + r0[1]; pb1 = linv + r1[1];
        pc0 = linv + r0[2]; pc1 = linv + r1[2];
        pd0 = linv + r0[3]; pd1 = linv + r1[3];
        pe0 = linv + r0[4]; pe1 = linv + r1[4];
    }
    v2f* const pw  = (v2f*)(part + 2 * lane);   // pair-partial writes; +64*k v2f
    v2f* const rs  = (v2f*)(part + 10 * lane);  // this lane's rows 2L,2L+1 (10 f32)
    v2f* const ivw = (v2f*)(linv + 2 * lane);   // inv write {invA, invB}

    float local = 0.0f;

    int q = wg;
    v4f rx0, rx1, rx2, rx3, rx4, rt0, rt1, rt2, rt3, rt4;
    if (q < nchunks) {
        const v4f* gx = (const v4f*)x   + (size_t)q * 320 + lane;
        const v4f* gt = (const v4f*)tgt + (size_t)q * 320 + lane;
        rx0 = NT(gx); rx1 = NT(gx + 64); rx2 = NT(gx + 128); rx3 = NT(gx + 192); rx4 = NT(gx + 256);
        rt0 = NT(gt); rt1 = NT(gt + 64); rt2 = NT(gt + 128); rt3 = NT(gt + 192); rt4 = NT(gt + 256);
    }

    while (q < nchunks) {
        int qn = q + W;
        bool pf = (qn < nchunks);
        v4f nx0, nx1, nx2, nx3, nx4, nt0, nt1, nt2, nt3, nt4;
        const v4f* gx = (const v4f*)x   + (size_t)qn * 320 + lane;
        const v4f* gt = (const v4f*)tgt + (size_t)qn * 320 + lane;
        if (pf) {   // x prefetch at top; t prefetch mid-iteration (pacing + reg window)
            nx0 = NT(gx); nx1 = NT(gx + 64); nx2 = NT(gx + 128); nx3 = NT(gx + 192); nx4 = NT(gx + 256);
        }

        // ---- phase A: exp elementwise (coalesced regs), pair-partials to LDS ----
        float e[2 * CCOL];
        EXP4(rx0, 0) EXP4(rx1, 4) EXP4(rx2, 8) EXP4(rx3, 12) EXP4(rx4, 16)
        // pair p = 128k + 2*lane (+1): pairs never straddle a row (rows start even).
        pw[0]   = (v2f){e[0]  + e[1],  e[2]  + e[3]};
        pw[64]  = (v2f){e[4]  + e[5],  e[6]  + e[7]};
        pw[128] = (v2f){e[8]  + e[9],  e[10] + e[11]};
        pw[192] = (v2f){e[12] + e[13], e[14] + e[15]};
        pw[256] = (v2f){e[16] + e[17], e[18] + e[19]};
        // wave-synchronous: compiler orders aliasing LDS ops

        // ---- row sums + inv for this lane's two rows ----
        v2f p0 = rs[0], p1 = rs[1], p2 = rs[2], p3 = rs[3], p4 = rs[4];
        float sA = p0.x + p0.y + p1.x + p1.y + p2.x;
        float sB = p2.y + p3.x + p3.y + p4.x + p4.y;
        float iA = ic[4], iB = ic[4];
#pragma unroll
        for (int k = 3; k >= 0; k--) { iA = fmaf(iA, sA, ic[k]); iB = fmaf(iB, sB, ic[k]); }
        for (int k = 0; k < niter; k++) {
            iA = iA * (2.0f - sA * iA);
            iB = iB * (2.0f - sB * iB);
        }
        ivw[0] = (v2f){iA, iB};

        if (pf) {
            nt0 = NT(gt); nt1 = NT(gt + 64); nt2 = NT(gt + 128); nt3 = NT(gt + 192); nt4 = NT(gt + 256);
        }

        // ---- inv broadcast (mostly same-address = free) + log/dot on coalesced t ----
        float i00 = *pa0, i10 = *pa1;
        float i01 = *pb0, i11 = *pb1;
        float i02 = *pc0, i12 = *pc1;
        float i03 = *pd0, i13 = *pd1;
        float i04 = *pe0, i14 = *pe1;

        LOGDOT(rt0, 0,  i00, i10)
        LOGDOT(rt1, 4,  i01, i11)
        LOGDOT(rt2, 8,  i02, i12)
        LOGDOT(rt3, 12, i03, i13)
        LOGDOT(rt4, 16, i04, i14)

        if (!pf) break;
        rx0 = nx0; rx1 = nx1; rx2 = nx2; rx3 = nx3; rx4 = nx4;
        rt0 = nt0; rt1 = nt1; rt2 = nt2; rt3 = nt3; rt4 = nt4;
        q = qn;
    }

    // ---- tail pairs (npairs % 64; zero for B=2e6) ----
    int tail0 = nchunks * 64;
    for (int p = tail0 + blockIdx.x * TPB + tid; p < npairs; p += gridDim.x * TPB) {
        const float* xp = x   + (size_t)p * 2 * CCOL;
        const float* tp = tgt + (size_t)p * 2 * CCOL;
#pragma unroll
        for (int r = 0; r < 2; r++) {
            float e2[CCOL], s = 0.0f;
#pragma unroll
            for (int c = 0; c < CCOL; c++) {
                float v = horner9(ec, xp[r * CCOL + c]);
                e2[c] = v; s += v;
            }
            float inv = ic[4];
#pragma unroll
            for (int k = 3; k >= 0; k--) inv = fmaf(inv, s, ic[k]);
            for (int k = 0; k < niter; k++) inv = inv * (2.0f - s * inv);
#pragma unroll
            for (int c = 0; c < CCOL; c++)
                local = fmaf(tp[r * CCOL + c], horner9(lc, e2[c] * inv), local);
        }
    }

    // ---- block reduction: shuffle -> LDS (reused post-barrier) -> one write ----
#pragma unroll
    for (int off = 32; off > 0; off >>= 1)
        local += __shfl_down(local, off, 64);

    __syncthreads();                          // all waves done with scratch LDS
    float* wsum = lds;
    if (lane == 0) wsum[w] = local;
    __syncthreads();
    if (tid == 0) {
        partials[blockIdx.x] = wsum[0] + wsum[1] + wsum[2] + wsum[3];
        __threadfence();                      // device-scope release (cross-XCD, G16)
        unsigned t = atomicAdd(&g_ticket, 1u);
        s_last = ((t % (unsigned)NBLOCKS) == (unsigned)(NBLOCKS - 1)) ? 1 : 0;
    }
    __syncthreads();

    // ---- last block: final reduction, identical tree to old reduce_kernel ----
    if (s_last) {
        __threadfence();                      // device-scope acquire before reading partials
        float v = 0.0f;
#pragma unroll
        for (int k = 0; k < NBLOCKS / TPB; k++)
            v += partials[tid + k * TPB];
#pragma unroll
        for (int off = 32; off > 0; off >>= 1)
            v += __shfl_down(v, off, 64);
        if (lane == 0) wsum[w] = v;           // safe: all prior wsum reads done (barrier above)
        __syncthreads();
        if (tid == 0)
            out[0] = (wsum[0] + wsum[1] + wsum[2] + wsum[3]) * neg_inv_b;
    }
}

extern "C" void kernel_launch(void* const* d_in, const int* in_sizes, int n_in,
                              void* d_out, int out_size, void* d_ws, size_t ws_size,
                              hipStream_t stream) {
    const float* x  = (const float*)d_in[0];
    const float* t  = (const float*)d_in[1];
    const float* ec = (const float*)d_in[2];
    const float* ic = (const float*)d_in[3];
    const float* lc = (const float*)d_in[4];
    const int*   it = (const int*)d_in[5];
    float* out = (float*)d_out;
    float* partials = (float*)d_ws;          // NBLOCKS floats

    int b_rows = in_sizes[0] / CCOL;         // 2,000,000
    int npairs = b_rows / 2;                 // 1,000,000
    int nchunks = npairs / 64;               // 15,625 (exact, no tail)
    float neg_inv_b = -1.0f / (float)b_rows;

    ce_kernel<<<NBLOCKS, TPB, 0, stream>>>(x, t, ec, ic, lc, it, partials, out,
                                           neg_inv_b, npairs, nchunks);
}

// Round 3
// 168.293 us; speedup vs baseline: 1.2638x; 1.2638x over previous
//
#include <hip/hip_runtime.h>

#define CCOL 10
#define TPB 256
#define NBLOCKS 1024            // persistent; 4 blocks/CU (LDS: 40960 B/block = 160KiB/CU)

// Native vector type: __builtin_nontemporal_load requires scalar/native-vector
// pointee (HIP's float4 is a struct and is rejected). Same 16B layout/alignment.
typedef float v4f __attribute__((ext_vector_type(4)));
#define NT(p) __builtin_nontemporal_load(p)   // zero-reuse stream: bypass cache fill path
// NT on BOTH streams is the measured optimum (R8: ~3.5 TB/s read vs 2.6 cached,
// 2.9 mixed). Depth-2 prefetch (R9) and split cached/NT (R10) both falsified.
// R11 (register-direct, no LDS staging): neutral (171.3) -> staging hop is free.
// R12 (fuse reduce via ticket/last-block): ce 46->77us. VGPR collapsed 128->60,
// prefetch pipeline destroyed; L3-hot replays ALSO 76us (issue-bound, not BW).
// Lesson: the 2-kernel artifact is codegen-fragile-free; do not touch the epilogue.

__device__ __forceinline__ float horner9(const float c[9], float x) {
    float v = c[8];
#pragma unroll
    for (int i = 7; i >= 0; i--) v = fmaf(v, x, c[i]);
    return v;
}

// exp-poly one v4f -> e[base..base+3]
#define EXP4(v, base)                          \
    e[(base) + 0] = horner9(ec, (v).x);        \
    e[(base) + 1] = horner9(ec, (v).y);        \
    e[(base) + 2] = horner9(ec, (v).z);        \
    e[(base) + 3] = horner9(ec, (v).w);

// log-poly + dot with target for one v4f (constant base -> inv select folds)
#define LOG4(tv, base)                                                    \
    {                                                                     \
        float i0 = ((base) + 0 < CCOL) ? inv0 : inv1;                     \
        float i1 = ((base) + 1 < CCOL) ? inv0 : inv1;                     \
        float i2 = ((base) + 2 < CCOL) ? inv0 : inv1;                     \
        float i3 = ((base) + 3 < CCOL) ? inv0 : inv1;                     \
        local = fmaf((tv).x, horner9(lc, e[(base) + 0] * i0), local);     \
        local = fmaf((tv).y, horner9(lc, e[(base) + 1] * i1), local);     \
        local = fmaf((tv).z, horner9(lc, e[(base) + 2] * i2), local);     \
        local = fmaf((tv).w, horner9(lc, e[(base) + 3] * i3), local);     \
    }

__global__ __launch_bounds__(TPB, 4) void ce_kernel(
    const float* __restrict__ x, const float* __restrict__ tgt,
    const float* __restrict__ exp_c, const float* __restrict__ inv_c,
    const float* __restrict__ log_c, const int* __restrict__ iters_p,
    float* __restrict__ partials, int npairs, int nchunks)
{
    // 4 waves * (320 x-v4f + 320 t-v4f) = 2560 v4f = 40960 B exactly.
    __shared__ v4f lds4[2560];

    // Coefficients: uniform -> SGPR broadcast (cached loads kept here).
    float ec[9], ic[5], lc[9];
#pragma unroll
    for (int i = 0; i < 9; i++) ec[i] = exp_c[i];
#pragma unroll
    for (int i = 0; i < 5; i++) ic[i] = inv_c[i];
#pragma unroll
    for (int i = 0; i < 9; i++) lc[i] = log_c[i];
    const int niter = iters_p[0];

    const int tid  = threadIdx.x;
    const int lane = tid & 63;
    const int w    = tid >> 6;
    const int wg   = blockIdx.x * 4 + w;      // global wave id
    const int W    = gridDim.x * 4;           // total waves

    v4f* lx = lds4 + w * 640;                 // this wave's x region (320 v4f)
    v4f* lt = lx + 320;                       // this wave's t region
    const v4f* bx = (const v4f*)((const float*)lx + lane * 20);  // lane's pair, 16B-aligned
    const v4f* bt = (const v4f*)((const float*)lt + lane * 20);

    float local = 0.0f;

    // ---- wave-private pipelined loop: chunk = 64 pairs = 5120 B per array ----
    // Prefetch in NAMED v4f regs (no alloca -> no scratch), NT loads (no cache fill).
    int q = wg;
    v4f rx0, rx1, rx2, rx3, rx4, rt0, rt1, rt2, rt3, rt4;
    if (q < nchunks) {
        const v4f* gx = (const v4f*)x   + (size_t)q * 320 + lane;
        const v4f* gt = (const v4f*)tgt + (size_t)q * 320 + lane;
        rx0 = NT(gx); rx1 = NT(gx + 64); rx2 = NT(gx + 128); rx3 = NT(gx + 192); rx4 = NT(gx + 256);
        rt0 = NT(gt); rt1 = NT(gt + 64); rt2 = NT(gt + 128); rt3 = NT(gt + 192); rt4 = NT(gt + 256);
    }

    while (q < nchunks) {
        // stage current chunk into wave-private LDS (wave-synchronous transpose;
        // no __syncthreads in hot loop -> no block-wide vmcnt(0) drain)
        v4f* sx = lx + lane;
        sx[0] = rx0; sx[64] = rx1; sx[128] = rx2; sx[192] = rx3; sx[256] = rx4;
        v4f* st = lt + lane;
        st[0] = rt0; st[64] = rt1; st[128] = rt2; st[192] = rt3; st[256] = rt4;

        // prefetch next chunk (stays in flight across compute)
        int qn = q + W;
        if (qn < nchunks) {
            const v4f* gx = (const v4f*)x   + (size_t)qn * 320 + lane;
            const v4f* gt = (const v4f*)tgt + (size_t)qn * 320 + lane;
            rx0 = NT(gx); rx1 = NT(gx + 64); rx2 = NT(gx + 128); rx3 = NT(gx + 192); rx4 = NT(gx + 256);
            rt0 = NT(gt); rt1 = NT(gt + 64); rt2 = NT(gt + 128); rt3 = NT(gt + 192); rt4 = NT(gt + 256);
        }

        // ---- compute: lane's own pair from LDS (stride 80 B, 0 conflicts measured) ----
        v4f a0 = bx[0], a1 = bx[1], a2 = bx[2], a3 = bx[3], a4 = bx[4];
        float e[2 * CCOL];
        EXP4(a0, 0) EXP4(a1, 4) EXP4(a2, 8) EXP4(a3, 12) EXP4(a4, 16)

        float s0 = 0.0f, s1 = 0.0f;
#pragma unroll
        for (int i = 0; i < CCOL; i++) s0 += e[i];
#pragma unroll
        for (int i = CCOL; i < 2 * CCOL; i++) s1 += e[i];

        float inv0 = ic[4], inv1 = ic[4];
#pragma unroll
        for (int k = 3; k >= 0; k--) {
            inv0 = fmaf(inv0, s0, ic[k]);
            inv1 = fmaf(inv1, s1, ic[k]);
        }
        for (int k = 0; k < niter; k++) {
            inv0 = inv0 * (2.0f - s0 * inv0);
            inv1 = inv1 * (2.0f - s1 * inv1);
        }

        v4f t0 = bt[0], t1 = bt[1], t2 = bt[2], t3 = bt[3], t4 = bt[4];
        LOG4(t0, 0) LOG4(t1, 4) LOG4(t2, 8) LOG4(t3, 12) LOG4(t4, 16)

        q = qn;
    }

    // ---- tail pairs (npairs % 64; zero for B=2e6) ----
    int tail0 = nchunks * 64;
    for (int p = tail0 + blockIdx.x * TPB + tid; p < npairs; p += gridDim.x * TPB) {
        const float* xp = x   + (size_t)p * 2 * CCOL;
        const float* tp = tgt + (size_t)p * 2 * CCOL;
#pragma unroll
        for (int r = 0; r < 2; r++) {
            float e2[CCOL], s = 0.0f;
#pragma unroll
            for (int c = 0; c < CCOL; c++) {
                float v = horner9(ec, xp[r * CCOL + c]);
                e2[c] = v; s += v;
            }
            float inv = ic[4];
#pragma unroll
            for (int k = 3; k >= 0; k--) inv = fmaf(inv, s, ic[k]);
            for (int k = 0; k < niter; k++) inv = inv * (2.0f - s * inv);
#pragma unroll
            for (int c = 0; c < CCOL; c++)
                local = fmaf(tp[r * CCOL + c], horner9(lc, e2[c] * inv), local);
        }
    }

    // ---- block reduction: shuffle -> LDS (reused post-barrier) -> one write ----
#pragma unroll
    for (int off = 32; off > 0; off >>= 1)
        local += __shfl_down(local, off, 64);

    __syncthreads();                          // all waves done with staging LDS
    float* wsum = (float*)lds4;
    if (lane == 0) wsum[w] = local;
    __syncthreads();
    if (tid == 0)
        partials[blockIdx.x] = wsum[0] + wsum[1] + wsum[2] + wsum[3];
}

__global__ __launch_bounds__(TPB) void reduce_kernel(
    const float* __restrict__ partials, float* __restrict__ out, float neg_inv_b)
{
    int tid = threadIdx.x;
    float local = 0.0f;
#pragma unroll
    for (int k = 0; k < NBLOCKS / TPB; k++)
        local += partials[tid + k * TPB];
#pragma unroll
    for (int off = 32; off > 0; off >>= 1)
        local += __shfl_down(local, off, 64);
    __shared__ float wsum[4];
    if ((tid & 63) == 0) wsum[tid >> 6] = local;
    __syncthreads();
    if (tid == 0)
        out[0] = (wsum[0] + wsum[1] + wsum[2] + wsum[3]) * neg_inv_b;
}

extern "C" void kernel_launch(void* const* d_in, const int* in_sizes, int n_in,
                              void* d_out, int out_size, void* d_ws, size_t ws_size,
                              hipStream_t stream) {
    const float* x  = (const float*)d_in[0];
    const float* t  = (const float*)d_in[1];
    const float* ec = (const float*)d_in[2];
    const float* ic = (const float*)d_in[3];
    const float* lc = (const float*)d_in[4];
    const int*   it = (const int*)d_in[5];
    float* out = (float*)d_out;
    float* partials = (float*)d_ws;          // NBLOCKS floats

    int b_rows = in_sizes[0] / CCOL;         // 2,000,000
    int npairs = b_rows / 2;                 // 1,000,000
    int nchunks = npairs / 64;               // 15,625 (exact, no tail)
    float neg_inv_b = -1.0f / (float)b_rows;

    ce_kernel<<<NBLOCKS, TPB, 0, stream>>>(x, t, ec, ic, lc, it, partials,
                                           npairs, nchunks);
    reduce_kernel<<<1, TPB, 0, stream>>>(partials, out, neg_inv_b);
}